// Round 1
// baseline (1209.629 us; speedup 1.0000x reference)
//
#include <hip/hip_runtime.h>
#include <cstdint>
#include <cstddef>

#define NH   16
#define DH   64
#define SQ   2048
#define NB   2
#define EM   1024
#define NREL 257   // 2*P+1, P=128

// ---------------------------------------------------------------------------
// GEMM: dst = A @ W^T + bias.  A:[M][K] row-major, W:[N][K] row-major.
// MODE 0: dst[m*N+n] (plain row-major)
// MODE 1: head-split: dst[((m/SQ)*NH + n/DH)*SQ*DH + (m%SQ)*DH + (n%DH)]
// 128x128 tile, BK=16, 256 threads, 8x8 per thread.
// ---------------------------------------------------------------------------
template<int MODE>
__global__ __launch_bounds__(256)
void gemm_nt(const float* __restrict__ A, const float* __restrict__ W,
             const float* __restrict__ bias, float* __restrict__ dst,
             int M, int N, int K)
{
    __shared__ float As[16][132];   // transposed: As[k][m], 132 keeps 16B row align
    __shared__ float Bs[16][132];   // transposed: Bs[k][n]
    const int t  = threadIdx.x;
    const int tx = t & 15, ty = t >> 4;
    const int n0 = blockIdx.x * 128;
    const int m0 = blockIdx.y * 128;

    float acc[8][8];
#pragma unroll
    for (int i = 0; i < 8; ++i)
#pragma unroll
        for (int j = 0; j < 8; ++j) acc[i][j] = 0.f;

    for (int k0 = 0; k0 < K; k0 += 16) {
#pragma unroll
        for (int l = 0; l < 2; ++l) {
            const int fid = t + l * 256;       // 0..511
            const int row = fid >> 2;          // 0..127
            const int cc  = fid & 3;           // float4 chunk within BK
            float4 av = *reinterpret_cast<const float4*>(
                A + (size_t)(m0 + row) * K + k0 + cc * 4);
            As[cc*4+0][row] = av.x; As[cc*4+1][row] = av.y;
            As[cc*4+2][row] = av.z; As[cc*4+3][row] = av.w;
            float4 bv = *reinterpret_cast<const float4*>(
                W + (size_t)(n0 + row) * K + k0 + cc * 4);
            Bs[cc*4+0][row] = bv.x; Bs[cc*4+1][row] = bv.y;
            Bs[cc*4+2][row] = bv.z; Bs[cc*4+3][row] = bv.w;
        }
        __syncthreads();
#pragma unroll
        for (int kk = 0; kk < 16; ++kk) {
            float4 a0 = *reinterpret_cast<const float4*>(&As[kk][ty * 8]);
            float4 a1 = *reinterpret_cast<const float4*>(&As[kk][ty * 8 + 4]);
            float4 b0 = *reinterpret_cast<const float4*>(&Bs[kk][tx * 8]);
            float4 b1 = *reinterpret_cast<const float4*>(&Bs[kk][tx * 8 + 4]);
            float a[8] = {a0.x,a0.y,a0.z,a0.w,a1.x,a1.y,a1.z,a1.w};
            float b[8] = {b0.x,b0.y,b0.z,b0.w,b1.x,b1.y,b1.z,b1.w};
#pragma unroll
            for (int i = 0; i < 8; ++i)
#pragma unroll
                for (int j = 0; j < 8; ++j)
                    acc[i][j] = fmaf(a[i], b[j], acc[i][j]);
        }
        __syncthreads();
    }

#pragma unroll
    for (int i = 0; i < 8; ++i) {
        const int m = m0 + ty * 8 + i;
#pragma unroll
        for (int j = 0; j < 8; ++j) {
            const int n = n0 + tx * 8 + j;
            const float vv = acc[i][j] + bias[n];
            if (MODE == 0) {
                dst[(size_t)m * N + n] = vv;
            } else {
                const int b  = m >> 11;        // m / SQ  (SQ=2048)
                const int s  = m & (SQ - 1);
                const int h  = n >> 6;         // n / DH
                const int dd = n & 63;
                dst[(((size_t)b * NH + h) * SQ + s) * DH + dd] = vv;
            }
        }
    }
}

// ---------------------------------------------------------------------------
// qrel[r][j] = dot(qh_row r, rk_table[j]),  r in [0, NB*NH*SQ), j in [0,257)
// One block = 64 rows; loops over 5 j-tiles of 64.
// ---------------------------------------------------------------------------
__global__ __launch_bounds__(256)
void qrel_gemm(const float* __restrict__ qh, const float* __restrict__ rk,
               float* __restrict__ qrel)
{
    __shared__ float Qs[64][68];   // transposed: Qs[d][row]
    __shared__ float Rs[64][68];   // transposed: Rs[d][j]
    const int t  = threadIdx.x;
    const int tx = t & 15, ty = t >> 4;
    const size_t r0 = (size_t)blockIdx.x * 64;

#pragma unroll
    for (int l = 0; l < 4; ++l) {
        const int fid = t + l * 256;          // 0..1023
        const int row = fid >> 4;             // 0..63
        const int c4  = fid & 15;
        float4 v = *reinterpret_cast<const float4*>(qh + (r0 + row) * DH + c4 * 4);
        Qs[c4*4+0][row] = v.x; Qs[c4*4+1][row] = v.y;
        Qs[c4*4+2][row] = v.z; Qs[c4*4+3][row] = v.w;
    }

    for (int jt = 0; jt < 5; ++jt) {
        const int j0 = jt * 64;
        __syncthreads();   // Qs staged (jt=0) / prior Rs reads done
#pragma unroll
        for (int l = 0; l < 4; ++l) {
            const int fid = t + l * 256;
            const int row = fid >> 4;
            const int c4  = fid & 15;
            float4 v = make_float4(0.f, 0.f, 0.f, 0.f);
            if (j0 + row < NREL)
                v = *reinterpret_cast<const float4*>(
                    rk + (size_t)(j0 + row) * DH + c4 * 4);
            Rs[c4*4+0][row] = v.x; Rs[c4*4+1][row] = v.y;
            Rs[c4*4+2][row] = v.z; Rs[c4*4+3][row] = v.w;
        }
        __syncthreads();

        float acc[4][4];
#pragma unroll
        for (int i = 0; i < 4; ++i)
#pragma unroll
            for (int j = 0; j < 4; ++j) acc[i][j] = 0.f;

#pragma unroll 8
        for (int kk = 0; kk < 64; ++kk) {
            float4 a = *reinterpret_cast<const float4*>(&Qs[kk][ty * 4]);
            float4 b = *reinterpret_cast<const float4*>(&Rs[kk][tx * 4]);
            float av[4] = {a.x, a.y, a.z, a.w};
            float bv[4] = {b.x, b.y, b.z, b.w};
#pragma unroll
            for (int i = 0; i < 4; ++i)
#pragma unroll
                for (int j = 0; j < 4; ++j)
                    acc[i][j] = fmaf(av[i], bv[j], acc[i][j]);
        }
#pragma unroll
        for (int i = 0; i < 4; ++i) {
            const size_t r = r0 + ty * 4 + i;
#pragma unroll
            for (int j = 0; j < 4; ++j) {
                const int jj = j0 + tx * 4 + j;
                if (jj < NREL) qrel[r * NREL + jj] = acc[i][j];
            }
        }
    }
}

// ---------------------------------------------------------------------------
// Fused attention per (b,h): 64 q-rows per block, k-tiles of 64.
// No max-subtraction (logits bounded ~±3): P = exp((qk + qrel)/8),
// accumulate l = sum P, w1 += P@V, w2 += P@rv_table[clip(k-q)+128].
// Far tiles (|k0-q0| >= 192): rv index constant -> w2 += rowsum(P)*rv_row.
// ---------------------------------------------------------------------------
__global__ __launch_bounds__(256)
void attn_fused(const float* __restrict__ qh, const float* __restrict__ kh,
                const float* __restrict__ vh, const float* __restrict__ qrel,
                const float* __restrict__ rv, float* __restrict__ wout)
{
    __shared__ float Qs[64][68];    // Q^T: Qs[d][q]
    __shared__ float KVs[64][68];   // K^T: KVs[d][k]  (reused as V natural [k][d])
    __shared__ float Ps[64][68];    // P^T: Ps[k][q]
    const int t  = threadIdx.x;
    const int tx = t & 15, ty = t >> 4;
    const int q0 = blockIdx.x * 64;
    const int bh = blockIdx.y;                    // b*NH + h
    const float* qb = qh   + (size_t)bh * SQ * DH;
    const float* kb = kh   + (size_t)bh * SQ * DH;
    const float* vb = vh   + (size_t)bh * SQ * DH;
    const float* qr = qrel + (size_t)bh * SQ * NREL;

#pragma unroll
    for (int l = 0; l < 4; ++l) {
        const int fid = t + l * 256;
        const int row = fid >> 4, c4 = fid & 15;
        float4 v = *reinterpret_cast<const float4*>(
            qb + (size_t)(q0 + row) * DH + c4 * 4);
        Qs[c4*4+0][row] = v.x; Qs[c4*4+1][row] = v.y;
        Qs[c4*4+2][row] = v.z; Qs[c4*4+3][row] = v.w;
    }

    float c1[4][4], c2[4][4], lacc[4];
#pragma unroll
    for (int i = 0; i < 4; ++i) {
        lacc[i] = 0.f;
#pragma unroll
        for (int j = 0; j < 4; ++j) { c1[i][j] = 0.f; c2[i][j] = 0.f; }
    }

    for (int k0 = 0; k0 < SQ; k0 += 64) {
        __syncthreads();   // prev iteration done with KVs(V) and Ps; Qs staged
        // stage K^T
#pragma unroll
        for (int l = 0; l < 4; ++l) {
            const int fid = t + l * 256;
            const int row = fid >> 4, c4 = fid & 15;
            float4 v = *reinterpret_cast<const float4*>(
                kb + (size_t)(k0 + row) * DH + c4 * 4);
            KVs[c4*4+0][row] = v.x; KVs[c4*4+1][row] = v.y;
            KVs[c4*4+2][row] = v.z; KVs[c4*4+3][row] = v.w;
        }
        __syncthreads();

        // S = Q K^T
        float s[4][4];
#pragma unroll
        for (int i = 0; i < 4; ++i)
#pragma unroll
            for (int j = 0; j < 4; ++j) s[i][j] = 0.f;
#pragma unroll 8
        for (int kk = 0; kk < 64; ++kk) {
            float4 a = *reinterpret_cast<const float4*>(&Qs[kk][ty * 4]);
            float4 b = *reinterpret_cast<const float4*>(&KVs[kk][tx * 4]);
            float av[4] = {a.x, a.y, a.z, a.w};
            float bv[4] = {b.x, b.y, b.z, b.w};
#pragma unroll
            for (int i = 0; i < 4; ++i)
#pragma unroll
                for (int j = 0; j < 4; ++j)
                    s[i][j] = fmaf(av[i], bv[j], s[i][j]);
        }

        const int rel0 = k0 - q0;
        const bool farlo = (rel0 <= -192);
        const bool farhi = (rel0 >= 192);

        // add rel-pos bias, scale, exp
        float rowsum[4] = {0.f, 0.f, 0.f, 0.f};
#pragma unroll
        for (int i = 0; i < 4; ++i) {
            const int qy = ty * 4 + i, qg = q0 + qy;
            const float* qrow = qr + (size_t)qg * NREL;
            if (farlo) {
                const float add = qrow[0];
#pragma unroll
                for (int j = 0; j < 4; ++j) s[i][j] += add;
            } else if (farhi) {
                const float add = qrow[256];
#pragma unroll
                for (int j = 0; j < 4; ++j) s[i][j] += add;
            } else {
#pragma unroll
                for (int j = 0; j < 4; ++j) {
                    const int kg = k0 + tx * 4 + j;
                    int rel = kg - qg;
                    rel = rel < -128 ? -128 : (rel > 128 ? 128 : rel);
                    s[i][j] += qrow[rel + 128];
                }
            }
#pragma unroll
            for (int j = 0; j < 4; ++j) {
                const float p = __expf(s[i][j] * 0.125f);
                s[i][j] = p;
                rowsum[i] += p;
            }
        }
        // row-sum across the 16-lane tx group (lanes of a row group are contiguous)
#pragma unroll
        for (int m = 1; m < 16; m <<= 1)
#pragma unroll
            for (int i = 0; i < 4; ++i)
                rowsum[i] += __shfl_xor(rowsum[i], m, 64);
#pragma unroll
        for (int i = 0; i < 4; ++i) lacc[i] += rowsum[i];

        // stage P^T
#pragma unroll
        for (int i = 0; i < 4; ++i)
#pragma unroll
            for (int j = 0; j < 4; ++j)
                Ps[tx * 4 + j][ty * 4 + i] = s[i][j];
        __syncthreads();   // S-GEMM reads of KVs done; Ps visible
        // stage V (natural [k][d], row stride 68 keeps float4 alignment)
#pragma unroll
        for (int l = 0; l < 4; ++l) {
            const int fid = t + l * 256;
            const int row = fid >> 4, c4 = fid & 15;
            float4 v = *reinterpret_cast<const float4*>(
                vb + (size_t)(k0 + row) * DH + c4 * 4);
            *reinterpret_cast<float4*>(&KVs[row][c4 * 4]) = v;
        }
        __syncthreads();

        if (farlo || farhi) {
            const int jc = farlo ? 0 : 256;
            float4 r4 = *reinterpret_cast<const float4*>(rv + (size_t)jc * DH + tx * 4);
#pragma unroll
            for (int i = 0; i < 4; ++i) {
                c2[i][0] = fmaf(rowsum[i], r4.x, c2[i][0]);
                c2[i][1] = fmaf(rowsum[i], r4.y, c2[i][1]);
                c2[i][2] = fmaf(rowsum[i], r4.z, c2[i][2]);
                c2[i][3] = fmaf(rowsum[i], r4.w, c2[i][3]);
            }
#pragma unroll 8
            for (int kt = 0; kt < 64; ++kt) {
                float4 pa = *reinterpret_cast<const float4*>(&Ps[kt][ty * 4]);
                float4 vv = *reinterpret_cast<const float4*>(&KVs[kt][tx * 4]);
                float pav[4] = {pa.x, pa.y, pa.z, pa.w};
                float vvv[4] = {vv.x, vv.y, vv.z, vv.w};
#pragma unroll
                for (int i = 0; i < 4; ++i)
#pragma unroll
                    for (int j = 0; j < 4; ++j)
                        c1[i][j] = fmaf(pav[i], vvv[j], c1[i][j]);
            }
        } else {
#pragma unroll 4
            for (int kt = 0; kt < 64; ++kt) {
                float4 pa = *reinterpret_cast<const float4*>(&Ps[kt][ty * 4]);
                float4 vv = *reinterpret_cast<const float4*>(&KVs[kt][tx * 4]);
                float pav[4] = {pa.x, pa.y, pa.z, pa.w};
                float vvv[4] = {vv.x, vv.y, vv.z, vv.w};
#pragma unroll
                for (int i = 0; i < 4; ++i) {
                    int rel = (k0 + kt) - (q0 + ty * 4 + i);
                    rel = rel < -128 ? -128 : (rel > 128 ? 128 : rel);
                    float4 r4 = *reinterpret_cast<const float4*>(
                        rv + (size_t)(rel + 128) * DH + tx * 4);
                    float rr[4] = {r4.x, r4.y, r4.z, r4.w};
#pragma unroll
                    for (int j = 0; j < 4; ++j) {
                        c1[i][j] = fmaf(pav[i], vvv[j], c1[i][j]);
                        c2[i][j] = fmaf(pav[i], rr[j],  c2[i][j]);
                    }
                }
            }
        }
    }

    // epilogue: w = (w1 + w2) / l, layout [B,S,H,DH] == [B,S,E]
    const int b = bh >> 4, h = bh & 15;
#pragma unroll
    for (int i = 0; i < 4; ++i) {
        const int qg  = q0 + ty * 4 + i;
        const float inv = 1.0f / lacc[i];
#pragma unroll
        for (int j = 0; j < 4; ++j) {
            const int dd = tx * 4 + j;
            wout[(((size_t)b * SQ + qg) * NH + h) * DH + dd] =
                (c1[i][j] + c2[i][j]) * inv;
        }
    }
}

// ---------------------------------------------------------------------------
extern "C" void kernel_launch(void* const* d_in, const int* in_sizes, int n_in,
                              void* d_out, int out_size, void* d_ws, size_t ws_size,
                              hipStream_t stream)
{
    const float* q  = (const float*)d_in[0];
    const float* k  = (const float*)d_in[1];
    const float* v  = (const float*)d_in[2];
    const float* Wq = (const float*)d_in[3];
    const float* bq = (const float*)d_in[4];
    const float* Wk = (const float*)d_in[5];
    const float* bk = (const float*)d_in[6];
    const float* Wv = (const float*)d_in[7];
    const float* bv = (const float*)d_in[8];
    const float* Wo = (const float*)d_in[9];
    const float* bo = (const float*)d_in[10];
    const float* rk = (const float*)d_in[11];
    const float* rv = (const float*)d_in[12];

    float* ws = (float*)d_ws;
    const size_t QN = (size_t)NB * NH * SQ * DH;   // 4,194,304 floats
    float* qhb  = ws;
    float* khb  = qhb + QN;
    float* vhb  = khb + QN;
    float* wbuf = vhb + QN;
    float* qrel = wbuf + QN;                       // [NB*NH*SQ][257]

    const int M = NB * SQ;                         // 4096
    dim3 gg(EM / 128, M / 128);                    // (8, 32)

    gemm_nt<1><<<gg, 256, 0, stream>>>(q, Wq, bq, qhb, M, EM, EM);
    gemm_nt<1><<<gg, 256, 0, stream>>>(k, Wk, bk, khb, M, EM, EM);
    gemm_nt<1><<<gg, 256, 0, stream>>>(v, Wv, bv, vhb, M, EM, EM);
    qrel_gemm<<<(NB * NH * SQ) / 64, 256, 0, stream>>>(qhb, rk, qrel);
    attn_fused<<<dim3(SQ / 64, NB * NH), 256, 0, stream>>>(qhb, khb, vhb, qrel, rv, wbuf);
    gemm_nt<0><<<gg, 256, 0, stream>>>(wbuf, Wo, bo, (float*)d_out, M, EM, EM);
}

// Round 2
// 322.115 us; speedup vs baseline: 3.7553x; 3.7553x over previous
//
#include <hip/hip_runtime.h>
#include <hip/hip_bf16.h>
#include <cstdint>
#include <cstddef>

#define NH   16
#define DH   64
#define SQ   2048
#define NB   2
#define EM   1024
#define NREL 257   // 2*P+1, P=128

typedef unsigned short ushort_t;
using bf16x8 = __attribute__((ext_vector_type(8))) __bf16;
using f32x4  = __attribute__((ext_vector_type(4))) float;

// D = A*B + C, A-lane row = l&15 (k=8*(l>>4)+j), B-lane col = l&15,
// C/D: col = l&15, row = 4*(l>>4)+reg   [verified layout per guide §3]
#define MFMA16(a, b, c) __builtin_amdgcn_mfma_f32_16x16x32_bf16(a, b, c, 0, 0, 0)

__device__ __forceinline__ unsigned short f2bf(float f) {
    union { float f; unsigned u; } x; x.f = f;
    unsigned r = x.u + 0x7FFFu + ((x.u >> 16) & 1u);   // RNE
    return (unsigned short)(r >> 16);
}
__device__ __forceinline__ float bf2f(unsigned short u) {
    union { unsigned u; float f; } x; x.u = ((unsigned)u) << 16;
    return x.f;
}

// ---------------------------------------------------------------------------
// f32 -> bf16 elementwise convert
// ---------------------------------------------------------------------------
__global__ __launch_bounds__(256) void cvt_bf16(const float* __restrict__ in,
                                                ushort_t* __restrict__ out, int n)
{
    int i = (blockIdx.x * 256 + threadIdx.x) * 4;
    const int stride = gridDim.x * 1024;
    for (; i < n; i += stride) {
        float4 v = *reinterpret_cast<const float4*>(in + i);
        ushort4 o;
        o.x = f2bf(v.x); o.y = f2bf(v.y); o.z = f2bf(v.z); o.w = f2bf(v.w);
        *reinterpret_cast<ushort4*>(out + i) = o;
    }
}

// rvT[d][c] = rv[c+1][d], bf16, c in [0,256): bucket c <-> rv row c+1
__global__ __launch_bounds__(256) void build_rvT(const float* __restrict__ rv,
                                                 ushort_t* __restrict__ rvT)
{
    int idx = blockIdx.x * 256 + threadIdx.x;
    if (idx < 64 * 256) {
        int d = idx >> 8, c = idx & 255;
        rvT[idx] = f2bf(rv[(size_t)(c + 1) * DH + d]);
    }
}

// ---------------------------------------------------------------------------
// bf16 NT GEMM: dst = A @ W^T + bias. A:[M][K], W:[N][K] bf16 row-major.
// 128x128 tile, BK=32, 4 waves each 64x64 (4x4 16x16 frags).
// LDS stride 40 elems (80B = 20 dwords % 32 -> conflict-free b128 reads).
// MODE 0: f32 dst[m*N+n]
// MODE 1: bf16 head-split [B,H,S,D]
// MODE 2: bf16 head-split transposed [B,H,D,S]  (for V)
// ---------------------------------------------------------------------------
template<int MODE>
__global__ __launch_bounds__(256)
void gemm_bt(const ushort_t* __restrict__ A, const ushort_t* __restrict__ W,
             const float* __restrict__ bias, void* __restrict__ dstv,
             int M, int N, int K)
{
    __shared__ ushort_t As[128 * 40];
    __shared__ ushort_t Bs[128 * 40];
    const int t = threadIdx.x, lane = t & 63;
    const int wv = t >> 6, wr = wv >> 1, wc = wv & 1;
    const int g = lane >> 4, c16 = lane & 15;
    const int n0 = blockIdx.x * 128, m0 = blockIdx.y * 128;

    f32x4 acc[4][4];
#pragma unroll
    for (int i = 0; i < 4; ++i)
#pragma unroll
        for (int j = 0; j < 4; ++j) acc[i][j] = (f32x4){0.f, 0.f, 0.f, 0.f};

    for (int k0 = 0; k0 < K; k0 += 32) {
        __syncthreads();
#pragma unroll
        for (int l = 0; l < 2; ++l) {
            const int fid = t + 256 * l;      // 0..511
            const int row = fid >> 2, ch = fid & 3;
            uint4 av = *reinterpret_cast<const uint4*>(A + (size_t)(m0 + row) * K + k0 + ch * 8);
            uint4 wv4 = *reinterpret_cast<const uint4*>(W + (size_t)(n0 + row) * K + k0 + ch * 8);
            *reinterpret_cast<uint4*>(As + row * 40 + ch * 8) = av;
            *reinterpret_cast<uint4*>(Bs + row * 40 + ch * 8) = wv4;
        }
        __syncthreads();

        bf16x8 af[4], bfr[4];
#pragma unroll
        for (int i = 0; i < 4; ++i)
            af[i] = *reinterpret_cast<const bf16x8*>(As + (wr * 64 + i * 16 + c16) * 40 + g * 8);
#pragma unroll
        for (int j = 0; j < 4; ++j)
            bfr[j] = *reinterpret_cast<const bf16x8*>(Bs + (wc * 64 + j * 16 + c16) * 40 + g * 8);
#pragma unroll
        for (int i = 0; i < 4; ++i)
#pragma unroll
            for (int j = 0; j < 4; ++j)
                acc[i][j] = MFMA16(af[i], bfr[j], acc[i][j]);
    }

#pragma unroll
    for (int j = 0; j < 4; ++j) {
        const int n = n0 + wc * 64 + j * 16 + c16;
        const float bn = bias[n];
#pragma unroll
        for (int i = 0; i < 4; ++i) {
#pragma unroll
            for (int r = 0; r < 4; ++r) {
                const int m = m0 + wr * 64 + i * 16 + 4 * g + r;
                const float vv = acc[i][j][r] + bn;
                if (MODE == 0) {
                    ((float*)dstv)[(size_t)m * N + n] = vv;
                } else {
                    const int b = m >> 11, s = m & (SQ - 1);
                    const int h = n >> 6, dd = n & 63;
                    if (MODE == 1)
                        ((ushort_t*)dstv)[(((size_t)b * NH + h) * SQ + s) * DH + dd] = f2bf(vv);
                    else
                        ((ushort_t*)dstv)[(((size_t)b * NH + h) * DH + dd) * SQ + s] = f2bf(vv);
                }
            }
        }
    }
}

// ---------------------------------------------------------------------------
// qrel[r][j] = dot(qh_row r (bf16), rk_table[j] (f32)), r in [0,65536), j<257
// f32 vector kernel (small: 2.2 GF)
// ---------------------------------------------------------------------------
__global__ __launch_bounds__(256)
void qrel_gemm(const ushort_t* __restrict__ qh, const float* __restrict__ rk,
               float* __restrict__ qrel)
{
    __shared__ float Qs[64][68];   // transposed: Qs[d][row]
    __shared__ float Rs[64][68];   // transposed: Rs[d][j]
    const int t  = threadIdx.x;
    const int tx = t & 15, ty = t >> 4;
    const size_t r0 = (size_t)blockIdx.x * 64;

#pragma unroll
    for (int l = 0; l < 2; ++l) {
        const int fid = t + l * 256;          // 0..511
        const int row = fid >> 3;             // 0..63
        const int ch  = fid & 7;              // 8 bf16 per chunk
        uint4 v = *reinterpret_cast<const uint4*>(qh + (r0 + row) * DH + ch * 8);
        const ushort_t* u = reinterpret_cast<const ushort_t*>(&v);
#pragma unroll
        for (int e = 0; e < 8; ++e) Qs[ch * 8 + e][row] = bf2f(u[e]);
    }

    for (int jt = 0; jt < 5; ++jt) {
        const int j0 = jt * 64;
        __syncthreads();
#pragma unroll
        for (int l = 0; l < 4; ++l) {
            const int fid = t + l * 256;
            const int row = fid >> 4;
            const int c4  = fid & 15;
            float4 v = make_float4(0.f, 0.f, 0.f, 0.f);
            if (j0 + row < NREL)
                v = *reinterpret_cast<const float4*>(rk + (size_t)(j0 + row) * DH + c4 * 4);
            Rs[c4*4+0][row] = v.x; Rs[c4*4+1][row] = v.y;
            Rs[c4*4+2][row] = v.z; Rs[c4*4+3][row] = v.w;
        }
        __syncthreads();

        float acc[4][4];
#pragma unroll
        for (int i = 0; i < 4; ++i)
#pragma unroll
            for (int j = 0; j < 4; ++j) acc[i][j] = 0.f;

#pragma unroll 8
        for (int kk = 0; kk < 64; ++kk) {
            float4 a = *reinterpret_cast<const float4*>(&Qs[kk][ty * 4]);
            float4 b = *reinterpret_cast<const float4*>(&Rs[kk][tx * 4]);
            float av[4] = {a.x, a.y, a.z, a.w};
            float bv[4] = {b.x, b.y, b.z, b.w};
#pragma unroll
            for (int i = 0; i < 4; ++i)
#pragma unroll
                for (int j = 0; j < 4; ++j)
                    acc[i][j] = fmaf(av[i], bv[j], acc[i][j]);
        }
#pragma unroll
        for (int i = 0; i < 4; ++i) {
            const size_t r = r0 + ty * 4 + i;
#pragma unroll
            for (int j = 0; j < 4; ++j) {
                const int jj = j0 + tx * 4 + j;
                if (jj < NREL) qrel[r * NREL + jj] = acc[i][j];
            }
        }
    }
}

// ---------------------------------------------------------------------------
// MFMA attention. Block = 64 q rows of one (b,h); 4 waves x 16 q rows.
// Per 64-k tile: S=QK^T (8 MFMA/wave), exp (f32, no max-sub: logits ~ +-2),
// route P: interior rel -> Pmass[q][rel+127] (unique slot), clipped -> reg
// buckets b0/b256; P -> Ps LDS; PV (8 MFMA/wave).
// End: w2 = Pmass @ rvT^T (32 MFMA/wave) + b0 * rv[0] vector term.
// LDS strides 72/264 elems (144B/528B = 4 mod 32 dwords -> conflict-free).
// ---------------------------------------------------------------------------
__global__ __launch_bounds__(256)
void attn_mfma(const ushort_t* __restrict__ qh, const ushort_t* __restrict__ kh,
               const ushort_t* __restrict__ vt, const float* __restrict__ qrel,
               const ushort_t* __restrict__ rvT, const float* __restrict__ rv_f32,
               ushort_t* __restrict__ wout)
{
    extern __shared__ char smem[];
    ushort_t* Pm = (ushort_t*)smem;                     // [64][264] bf16
    ushort_t* Ks = (ushort_t*)(smem + 33792);           // [64][72]
    ushort_t* Vs = (ushort_t*)(smem + 33792 + 9216);    // [64][72]  (V^T: row=d)
    ushort_t* Ps = (ushort_t*)(smem + 33792 + 18432);   // [64][72]
    ushort_t* Qs = (ushort_t*)(smem + 33792 + 27648);   // [64][72]
    ushort_t* Rv = (ushort_t*)(smem + 33792);           // [64][264] alias (epilogue)

    const int t = threadIdx.x, lane = t & 63, w = t >> 6;
    const int g = lane >> 4, c16 = lane & 15;
    const int q0 = blockIdx.x * 64, bh = blockIdx.y;

    // zero Pmass (interior slots never written for edge q-rows must be 0)
    for (int i = t; i < 8448; i += 256) ((unsigned*)Pm)[i] = 0u;

    // stage Q tile [64][64] -> LDS, then fragments to registers
#pragma unroll
    for (int l = 0; l < 2; ++l) {
        const int fid = t + 256 * l;
        const int row = fid >> 3, ch = fid & 7;
        uint4 v = *reinterpret_cast<const uint4*>(
            qh + ((size_t)bh * SQ + q0 + row) * DH + ch * 8);
        *reinterpret_cast<uint4*>(Qs + row * 72 + ch * 8) = v;
    }
    __syncthreads();
    bf16x8 qf[2];
#pragma unroll
    for (int ks = 0; ks < 2; ++ks)
        qf[ks] = *reinterpret_cast<const bf16x8*>(Qs + (w * 16 + c16) * 72 + ks * 32 + g * 8);

    // far-tile bias constants (qrel cols 0 and 256) for this lane's 4 rows
    const float* qrb = qrel + ((size_t)bh * SQ + q0) * NREL;
    float q0add[4], q256add[4];
#pragma unroll
    for (int i = 0; i < 4; ++i) {
        const int r = w * 16 + 4 * g + i;
        q0add[i]   = qrb[(size_t)r * NREL + 0];
        q256add[i] = qrb[(size_t)r * NREL + 256];
    }

    f32x4 w1[4];
#pragma unroll
    for (int n = 0; n < 4; ++n) w1[n] = (f32x4){0.f, 0.f, 0.f, 0.f};
    float lac[4]  = {0.f, 0.f, 0.f, 0.f};
    float b0[4]   = {0.f, 0.f, 0.f, 0.f};
    float b256[4] = {0.f, 0.f, 0.f, 0.f};

    for (int k0 = 0; k0 < SQ; k0 += 64) {
        __syncthreads();   // prev tile's MFMA reads of Ks/Vs done
#pragma unroll
        for (int l = 0; l < 2; ++l) {
            const int fid = t + 256 * l;
            const int row = fid >> 3, ch = fid & 7;
            uint4 kv = *reinterpret_cast<const uint4*>(
                kh + ((size_t)bh * SQ + k0 + row) * DH + ch * 8);
            *reinterpret_cast<uint4*>(Ks + row * 72 + ch * 8) = kv;
            uint4 vv = *reinterpret_cast<const uint4*>(
                vt + ((size_t)bh * DH + row) * SQ + k0 + ch * 8);
            *reinterpret_cast<uint4*>(Vs + row * 72 + ch * 8) = vv;
        }
        __syncthreads();

        // S = Q K^T : rows q (wave strip), cols k (16n + c16)
        f32x4 s[4];
#pragma unroll
        for (int n = 0; n < 4; ++n) s[n] = (f32x4){0.f, 0.f, 0.f, 0.f};
#pragma unroll
        for (int ks = 0; ks < 2; ++ks)
#pragma unroll
            for (int n = 0; n < 4; ++n) {
                bf16x8 kf = *reinterpret_cast<const bf16x8*>(
                    Ks + (16 * n + c16) * 72 + ks * 32 + g * 8);
                s[n] = MFMA16(qf[ks], kf, s[n]);
            }

        const int rel0 = k0 - q0;
        float rsum[4] = {0.f, 0.f, 0.f, 0.f};
        if (rel0 <= -192 || rel0 >= 192) {
            const bool lo = rel0 < 0;
#pragma unroll
            for (int i = 0; i < 4; ++i) {
                const float add = lo ? q0add[i] : q256add[i];
#pragma unroll
                for (int n = 0; n < 4; ++n) {
                    const float p = __expf((s[n][i] + add) * 0.125f);
                    s[n][i] = p; rsum[i] += p;
                }
                if (lo) b0[i] += rsum[i] - 0.f; // accumulated below uniformly
            }
            if (!lo) { b256[0] += rsum[0]; b256[1] += rsum[1]; b256[2] += rsum[2]; b256[3] += rsum[3]; }
            else     { /* b0 handled above per-i: fix to uniform form */ }
            if (lo)  { /* b0 already incremented inside loop */ }
        } else {
#pragma unroll
            for (int i = 0; i < 4; ++i) {
                const int qloc = w * 16 + 4 * g + i;
                const float* qrow = qrb + (size_t)qloc * NREL;
#pragma unroll
                for (int n = 0; n < 4; ++n) {
                    const int rel = (k0 + 16 * n + c16) - (q0 + qloc);
                    float add;
                    if (rel <= -128)     add = q0add[i];
                    else if (rel >= 128) add = q256add[i];
                    else                 add = qrow[rel + 128];
                    const float p = __expf((s[n][i] + add) * 0.125f);
                    s[n][i] = p; rsum[i] += p;
                    if (rel <= -128)      b0[i] += p;
                    else if (rel >= 128)  b256[i] += p;
                    else Pm[(size_t)qloc * 264 + rel + 127] = f2bf(p);
                }
            }
        }
#pragma unroll
        for (int i = 0; i < 4; ++i) lac[i] += rsum[i];

        // stage P (bf16) into own wave's Ps rows
#pragma unroll
        for (int i = 0; i < 4; ++i)
#pragma unroll
            for (int n = 0; n < 4; ++n)
                Ps[(w * 16 + 4 * g + i) * 72 + 16 * n + c16] = f2bf(s[n][i]);

        // w1 += P @ V  (A-frag rows are own wave's Ps rows -> intra-wave dep)
#pragma unroll
        for (int ks = 0; ks < 2; ++ks) {
            bf16x8 pf = *reinterpret_cast<const bf16x8*>(
                Ps + (w * 16 + c16) * 72 + ks * 32 + g * 8);
#pragma unroll
            for (int n = 0; n < 4; ++n) {
                bf16x8 vf = *reinterpret_cast<const bf16x8*>(
                    Vs + (16 * n + c16) * 72 + ks * 32 + g * 8);
                w1[n] = MFMA16(pf, vf, w1[n]);
            }
        }
    }

    // reduce row stats across the 16-lane column group
#pragma unroll
    for (int m = 1; m < 16; m <<= 1) {
#pragma unroll
        for (int i = 0; i < 4; ++i) {
            lac[i]  += __shfl_xor(lac[i],  m, 64);
            b0[i]   += __shfl_xor(b0[i],   m, 64);
            b256[i] += __shfl_xor(b256[i], m, 64);
        }
    }

    __syncthreads();   // all waves done with Ks/Vs/Ps/Qs before Rv alias write
    if (c16 == 0) {
#pragma unroll
        for (int i = 0; i < 4; ++i)
            Pm[(size_t)(w * 16 + 4 * g + i) * 264 + 255] = f2bf(b256[i]);
    }
    // stage rvT [64][256] -> Rv [64][264]
#pragma unroll
    for (int l = 0; l < 8; ++l) {
        const int fid = t + 256 * l;          // 0..2047
        const int row = fid >> 5, ch = fid & 31;
        uint4 v = *reinterpret_cast<const uint4*>(rvT + row * 256 + ch * 8);
        *reinterpret_cast<uint4*>(Rv + row * 264 + ch * 8) = v;
    }
    __syncthreads();

    // w2: acc += Pmass @ rvT^T  (buckets 1..256; bucket0 via vector term)
#pragma unroll
    for (int ks = 0; ks < 8; ++ks) {
        bf16x8 pm = *reinterpret_cast<const bf16x8*>(
            Pm + (w * 16 + c16) * 264 + ks * 32 + g * 8);
#pragma unroll
        for (int n = 0; n < 4; ++n) {
            bf16x8 rf = *reinterpret_cast<const bf16x8*>(
                Rv + (16 * n + c16) * 264 + ks * 32 + g * 8);
            w1[n] = MFMA16(pm, rf, w1[n]);
        }
    }

    // epilogue: + b0*rv[0][d], normalize by lac, store bf16 [B,S,H,D]
    const int b = bh >> 4, h = bh & 15;
#pragma unroll
    for (int n = 0; n < 4; ++n) {
        const int col = 16 * n + c16;
        const float rv0 = rv_f32[col];        // rv row 0 (f32 input)
#pragma unroll
        for (int i = 0; i < 4; ++i) {
            const float val = (w1[n][i] + b0[i] * rv0) / lac[i];
            const int qg = q0 + w * 16 + 4 * g + i;
            wout[(((size_t)b * SQ + qg) * NH + h) * DH + col] = f2bf(val);
        }
    }
}

// ---------------------------------------------------------------------------
extern "C" void kernel_launch(void* const* d_in, const int* in_sizes, int n_in,
                              void* d_out, int out_size, void* d_ws, size_t ws_size,
                              hipStream_t stream)
{
    const float* q  = (const float*)d_in[0];
    const float* k  = (const float*)d_in[1];
    const float* v  = (const float*)d_in[2];
    const float* Wq = (const float*)d_in[3];
    const float* bq = (const float*)d_in[4];
    const float* Wk = (const float*)d_in[5];
    const float* bk = (const float*)d_in[6];
    const float* Wv = (const float*)d_in[7];
    const float* bv = (const float*)d_in[8];
    const float* Wo = (const float*)d_in[9];
    const float* bo = (const float*)d_in[10];
    const float* rk = (const float*)d_in[11];
    const float* rv = (const float*)d_in[12];

    char* ws = (char*)d_ws;
    auto alloc = [&](size_t bytes) { char* p = ws; ws += bytes; return p; };
    const size_t QB = (size_t)NB * SQ * EM * 2;      // 8388608 B (bf16 [4096][1024])
    const size_t WB = (size_t)EM * EM * 2;           // 2097152 B

    ushort_t* qbf  = (ushort_t*)alloc(QB);
    ushort_t* kbf  = (ushort_t*)alloc(QB);
    ushort_t* vbf  = (ushort_t*)alloc(QB);
    ushort_t* Wqb  = (ushort_t*)alloc(WB);
    ushort_t* Wkb  = (ushort_t*)alloc(WB);
    ushort_t* Wvb  = (ushort_t*)alloc(WB);
    ushort_t* Wob  = (ushort_t*)alloc(WB);
    ushort_t* qhb  = (ushort_t*)alloc(QB);           // [B,H,S,D]
    ushort_t* khb  = (ushort_t*)alloc(QB);           // [B,H,S,D]
    ushort_t* vtb  = (ushort_t*)alloc(QB);           // [B,H,D,S]
    ushort_t* wbuf = (ushort_t*)alloc(QB);           // [B,S,H,D] = [4096][1024]
    ushort_t* rvT  = (ushort_t*)alloc(64 * 256 * 2);
    float*    qrel = (float*)alloc((size_t)NB * NH * SQ * NREL * 4);

    const int NQ = NB * SQ * EM;                     // 4194304
    const int NW = EM * EM;                          // 1048576
    cvt_bf16<<<2048, 256, 0, stream>>>(q, qbf, NQ);
    cvt_bf16<<<2048, 256, 0, stream>>>(k, kbf, NQ);
    cvt_bf16<<<2048, 256, 0, stream>>>(v, vbf, NQ);
    cvt_bf16<<<1024, 256, 0, stream>>>(Wq, Wqb, NW);
    cvt_bf16<<<1024, 256, 0, stream>>>(Wk, Wkb, NW);
    cvt_bf16<<<1024, 256, 0, stream>>>(Wv, Wvb, NW);
    cvt_bf16<<<1024, 256, 0, stream>>>(Wo, Wob, NW);
    build_rvT<<<64, 256, 0, stream>>>(rv, rvT);

    const int M = NB * SQ;                           // 4096
    dim3 gg(EM / 128, M / 128);                      // (8, 32)
    gemm_bt<1><<<gg, 256, 0, stream>>>(qbf, Wqb, bq, qhb, M, EM, EM);
    gemm_bt<1><<<gg, 256, 0, stream>>>(kbf, Wkb, bk, khb, M, EM, EM);
    gemm_bt<2><<<gg, 256, 0, stream>>>(vbf, Wvb, bv, vtb, M, EM, EM);
    qrel_gemm<<<(NB * NH * SQ) / 64, 256, 0, stream>>>(qhb, rk, qrel);
    attn_mfma<<<dim3(SQ / 64, NB * NH), 256, 70656, stream>>>(
        qhb, khb, vtb, qrel, rvT, rv, wbuf);
    gemm_bt<0><<<gg, 256, 0, stream>>>(wbuf, Wob, bo, d_out, M, EM, EM);
}